// Round 7
// baseline (607.969 us; speedup 1.0000x reference)
//
#include <hip/hip_runtime.h>
#include <hip/hip_bf16.h>

// ---------------------------------------------------------------------------
// GNN Residual Feature Extractor
//   x = embed(type features)                       [N,32]
//   x1 = gcn(x, W1)+b1                             [N,64]
//   h  = relu(gcn(relu(x1),W2)+b2)                 [N,128]
//   h  = relu(gcn(h,W3)+b3) + x1                   [N,64]
//   out = segment_mean(h, batch)                   [100,64]
//
// gcn agg commutes with weight multiply; aggregate on narrow side.
// Gather TABLES are bf16 (packed u32 pairs), PRE-SCALED by dinv and
// pre-activated by their producers; accumulation stays f32.
// Residual x1 is stored bf16 (x1b).
//
// CSR build: atomic-free two-pass radix partition (bin = dst>>10), pairs
// packed into one u32 (src<<10 | dst&1023).
//
// R7: k_mmt = LDS-tiled mm (R6's k_mm was latency-bound at 9% occupancy:
// per-thread row registers -> 64-line uncoalesced loads + VGPR 140).
// ---------------------------------------------------------------------------

#define THREADS 256
#define BINSHIFT 10
#define EPBA 4096        // edges per partition block
#define SCANCH 8         // k_scanrows: values per thread (supports <=2048 blocks)

// ---------------- bf16 helpers ----------------
__device__ __forceinline__ unsigned bfpack2(float lo, float hi) {
    unsigned ul = __float_as_uint(lo);
    unsigned uh = __float_as_uint(hi);
    ul = (ul + 0x7fffu + ((ul >> 16) & 1u)) >> 16;          // rne, low half
    uh = (uh + 0x7fffu + ((uh >> 16) & 1u)) & 0xffff0000u;  // rne, high half
    return ul | uh;
}

__device__ __forceinline__ void bfacc(uint2 v, float& a0, float& a1,
                                      float& a2, float& a3) {
    a0 += __uint_as_float(v.x << 16);
    a1 += __uint_as_float(v.x & 0xffff0000u);
    a2 += __uint_as_float(v.y << 16);
    a3 += __uint_as_float(v.y & 0xffff0000u);
}

// ---------------- pass 1: per-(block,bin) exact counts ----------------
__global__ __launch_bounds__(THREADS)
void k_partcnt(const int* __restrict__ dst, int* __restrict__ counts,
               int nblk_part, int nb, int e) {
    extern __shared__ int h[];
    int t = threadIdx.x;
    for (int i = t; i < nb; i += THREADS) h[i] = 0;
    __syncthreads();
    int lo = blockIdx.x * EPBA;
    int hi = min(lo + EPBA, e);
    for (int i = lo + t; i < hi; i += THREADS)
        atomicAdd(&h[dst[i] >> BINSHIFT], 1);
    __syncthreads();
    for (int i = t; i < nb; i += THREADS)
        counts[(size_t)i * nblk_part + blockIdx.x] = h[i];
}

// ---------------- scan each bin's row of per-block counts ----------------
__global__ __launch_bounds__(THREADS)
void k_scanrows(int* __restrict__ counts, int* __restrict__ bintot, int nblk_part) {
    __shared__ int wsum[THREADS];
    int* row = counts + (size_t)blockIdx.x * nblk_part;
    int t = threadIdx.x;
    int base = t * SCANCH;
    int v[SCANCH];
    int s = 0;
#pragma unroll
    for (int k = 0; k < SCANCH; ++k) {
        v[k] = (base + k < nblk_part) ? row[base + k] : 0;
        s += v[k];
    }
    wsum[t] = s;
    __syncthreads();
    for (int off = 1; off < THREADS; off <<= 1) {
        int a = (t >= off) ? wsum[t - off] : 0;
        __syncthreads();
        wsum[t] += a;
        __syncthreads();
    }
    int run = wsum[t] - s;  // exclusive
#pragma unroll
    for (int k = 0; k < SCANCH; ++k) {
        int c = v[k];
        if (base + k < nblk_part) row[base + k] = run;
        run += c;
    }
    if (t == THREADS - 1) bintot[blockIdx.x] = run;
}

// ---------------- scan bin totals (single block, nb<=128) ----------------
__global__ __launch_bounds__(128)
void k_binscan(const int* __restrict__ bintot, int* __restrict__ binptr,
               int nb, int e) {
    __shared__ int lds[128];
    int t = threadIdx.x;
    int v = (t < nb) ? bintot[t] : 0;
    lds[t] = v;
    __syncthreads();
    for (int off = 1; off < 128; off <<= 1) {
        int a = (t >= off) ? lds[t - off] : 0;
        __syncthreads();
        lds[t] += a;
        __syncthreads();
    }
    if (t < nb) binptr[t] = lds[t] - v;  // exclusive
    if (t == 0) binptr[nb] = e;
}

// ---------------- pass 2: deterministic partition write (packed u32) --------
__global__ __launch_bounds__(THREADS)
void k_partwrite(const int* __restrict__ src, const int* __restrict__ dst,
                 const int* __restrict__ binptr, const int* __restrict__ counts,
                 int nblk_part, unsigned* __restrict__ pairs, int nb, int e) {
    extern __shared__ int smem[];
    int* base = smem;       // nb
    int* cnt  = smem + nb;  // nb
    int t = threadIdx.x;
    for (int i = t; i < nb; i += THREADS) {
        base[i] = binptr[i] + counts[(size_t)i * nblk_part + blockIdx.x];
        cnt[i] = 0;
    }
    __syncthreads();
    int lo = blockIdx.x * EPBA;
    int hi = min(lo + EPBA, e);
    for (int i = lo + t; i < hi; i += THREADS) {
        int s = src[i], d = dst[i];
        int b = d >> BINSHIFT;
        int pos = atomicAdd(&cnt[b], 1);   // LDS only
        pairs[base[b] + pos] = ((unsigned)s << BINSHIFT) | (unsigned)(d & ((1 << BINSHIFT) - 1));
    }
}

// ---------------- per-bin CSR finalize ----------------
__global__ __launch_bounds__(THREADS)
void k_bincsr(const unsigned* __restrict__ pairs, const int* __restrict__ binptr,
              int* __restrict__ rowptr, float* __restrict__ dinv,
              int* __restrict__ srcs, int n, int nb, int e) {
    __shared__ int lcnt[1024];
    __shared__ int lofs[1024];
    __shared__ int wsum[THREADS];
    int b = blockIdx.x, t = threadIdx.x;
    int e0 = binptr[b], e1 = binptr[b + 1];
    int n0 = b << BINSHIFT;
    for (int i = t; i < 1024; i += THREADS) lcnt[i] = 0;
    __syncthreads();
    for (int j = e0 + t; j < e1; j += THREADS)
        atomicAdd(&lcnt[pairs[j] & 1023u], 1);
    __syncthreads();
    int c0 = lcnt[4 * t + 0], c1 = lcnt[4 * t + 1];
    int c2 = lcnt[4 * t + 2], c3 = lcnt[4 * t + 3];
    int s = c0 + c1 + c2 + c3;
    wsum[t] = s;
    __syncthreads();
    for (int off = 1; off < THREADS; off <<= 1) {
        int a = (t >= off) ? wsum[t - off] : 0;
        __syncthreads();
        wsum[t] += a;
        __syncthreads();
    }
    int excl = wsum[t] - s;
    lofs[4 * t + 0] = excl;
    lofs[4 * t + 1] = excl + c0;
    lofs[4 * t + 2] = excl + c0 + c1;
    lofs[4 * t + 3] = excl + c0 + c1 + c2;
    __syncthreads();
    for (int i = t; i < 1024; i += THREADS) {
        int node = n0 + i;
        if (node < n) {
            rowptr[node] = e0 + lofs[i];
            dinv[node] = rsqrtf((float)lcnt[i] + 1.0f);
        }
    }
    if (b == nb - 1 && t == 0) rowptr[n] = e;
    __syncthreads();
    for (int j = e0 + t; j < e1; j += THREADS) {
        unsigned pp = pairs[j];
        int pos = e0 + atomicAdd(&lofs[pp & 1023u], 1);
        srcs[pos] = (int)(pp >> BINSHIFT);
    }
}

// ---------------- embedding: xb[idx[r]] = bf16(dinv * (f[r] @ W + b)) --------
template <int K>
__global__ __launch_bounds__(THREADS)
void k_embed(const float* __restrict__ f, const float* __restrict__ W,
             const float* __restrict__ b, const int* __restrict__ idx,
             const float* __restrict__ dinv, int rows, unsigned* __restrict__ xb) {
    int g = blockIdx.x * THREADS + threadIdx.x;
    int r = g >> 4, cp = g & 15;
    if (r >= rows) return;
    int node = idx[r];
    float dv = dinv[node];
    float a0 = b[2 * cp], a1 = b[2 * cp + 1];
#pragma unroll
    for (int k = 0; k < K; ++k) {
        float fv = f[r * K + k];
        a0 += fv * W[k * 32 + 2 * cp];
        a1 += fv * W[k * 32 + 2 * cp + 1];
    }
    xb[(size_t)node * 16 + cp] = bfpack2(dv * a0, dv * a1);
}

// ---------------- gather (bf16 table, row=128B): one wave per node ----------
// 4 quarter-groups of 16 lanes; each quarter owns one edge's full row.
// out[i] = dv_i * (tbl[i] + sum_s tbl[s])  [+bias][relu][+resid(bf16)], f32 out.
template <bool HASBIAS, bool OUTRELU, bool HASRES>
__global__ __launch_bounds__(THREADS)
void k_gather64(const unsigned* __restrict__ tblb, const int* __restrict__ rowptr,
                const int* __restrict__ srcs, const float* __restrict__ dinv,
                const float* __restrict__ bias, const unsigned* __restrict__ resid,
                float* __restrict__ out, int n) {
    int gt = blockIdx.x * THREADS + threadIdx.x;
    int node = gt >> 6;
    int lane = threadIdx.x & 63;
    if (node >= n) return;
    int qw = lane >> 4, li = lane & 15;
    const uint2* t2 = reinterpret_cast<const uint2*>(tblb);
    float a0 = 0.f, a1 = 0.f, a2 = 0.f, a3 = 0.f;
    int beg = rowptr[node], end = rowptr[node + 1];
    int j = beg;
    for (; j + 16 <= end; j += 16) {          // 16 edges, 4 rows in flight
        int i0 = srcs[j + qw];
        int i1 = srcs[j + 4 + qw];
        int i2 = srcs[j + 8 + qw];
        int i3 = srcs[j + 12 + qw];
        uint2 v0 = t2[(size_t)i0 * 16 + li];
        uint2 v1 = t2[(size_t)i1 * 16 + li];
        uint2 v2 = t2[(size_t)i2 * 16 + li];
        uint2 v3 = t2[(size_t)i3 * 16 + li];
        bfacc(v0, a0, a1, a2, a3);
        bfacc(v1, a0, a1, a2, a3);
        bfacc(v2, a0, a1, a2, a3);
        bfacc(v3, a0, a1, a2, a3);
    }
    for (; j + 8 <= end; j += 8) {
        int i0 = srcs[j + qw];
        int i1 = srcs[j + 4 + qw];
        uint2 v0 = t2[(size_t)i0 * 16 + li];
        uint2 v1 = t2[(size_t)i1 * 16 + li];
        bfacc(v0, a0, a1, a2, a3);
        bfacc(v1, a0, a1, a2, a3);
    }
    int rem = end - j;
    if (qw < rem) {
        uint2 v = t2[(size_t)srcs[j + qw] * 16 + li];
        bfacc(v, a0, a1, a2, a3);
    }
    if (qw + 4 < rem) {
        uint2 v = t2[(size_t)srcs[j + 4 + qw] * 16 + li];
        bfacc(v, a0, a1, a2, a3);
    }
    a0 += __shfl_down(a0, 32, 64); a1 += __shfl_down(a1, 32, 64);
    a2 += __shfl_down(a2, 32, 64); a3 += __shfl_down(a3, 32, 64);
    a0 += __shfl_down(a0, 16, 64); a1 += __shfl_down(a1, 16, 64);
    a2 += __shfl_down(a2, 16, 64); a3 += __shfl_down(a3, 16, 64);
    if (lane < 16) {
        uint2 sv = t2[(size_t)node * 16 + li];
        bfacc(sv, a0, a1, a2, a3);
        float dv = dinv[node];
        float r0 = dv * a0, r1 = dv * a1, r2 = dv * a2, r3 = dv * a3;
        if (HASBIAS) {
            float4 bv = *reinterpret_cast<const float4*>(bias + 4 * li);
            r0 += bv.x; r1 += bv.y; r2 += bv.z; r3 += bv.w;
        }
        if (OUTRELU) {
            r0 = fmaxf(r0, 0.f); r1 = fmaxf(r1, 0.f);
            r2 = fmaxf(r2, 0.f); r3 = fmaxf(r3, 0.f);
        }
        if (HASRES) {
            uint2 rv = reinterpret_cast<const uint2*>(resid)[(size_t)node * 16 + li];
            bfacc(rv, r0, r1, r2, r3);
        }
        float4 o = {r0, r1, r2, r3};
        reinterpret_cast<float4*>(out)[(size_t)node * 16 + li] = o;
    }
}

// ---------------- gather (bf16 table, row=64B): 8 groups of 8 lanes ---------
__global__ __launch_bounds__(THREADS)
void k_gather32(const unsigned* __restrict__ tblb, const int* __restrict__ rowptr,
                const int* __restrict__ srcs, const float* __restrict__ dinv,
                float* __restrict__ out, int n) {
    int gt = blockIdx.x * THREADS + threadIdx.x;
    int node = gt >> 6;
    int lane = threadIdx.x & 63;
    if (node >= n) return;
    int og = lane >> 3, li = lane & 7;
    const uint2* t2 = reinterpret_cast<const uint2*>(tblb);
    float a0 = 0.f, a1 = 0.f, a2 = 0.f, a3 = 0.f;
    int beg = rowptr[node], end = rowptr[node + 1];
    int j = beg;
    for (; j + 16 <= end; j += 16) {          // 16 edges, 2 rows in flight/lane
        int i0 = srcs[j + og];
        int i1 = srcs[j + 8 + og];
        uint2 v0 = t2[(size_t)i0 * 8 + li];
        uint2 v1 = t2[(size_t)i1 * 8 + li];
        bfacc(v0, a0, a1, a2, a3);
        bfacc(v1, a0, a1, a2, a3);
    }
    for (; j + 8 <= end; j += 8) {
        int i0 = srcs[j + og];
        uint2 v0 = t2[(size_t)i0 * 8 + li];
        bfacc(v0, a0, a1, a2, a3);
    }
    int rem = end - j;
    if (og < rem) {
        uint2 v = t2[(size_t)srcs[j + og] * 8 + li];
        bfacc(v, a0, a1, a2, a3);
    }
    a0 += __shfl_down(a0, 32, 64); a1 += __shfl_down(a1, 32, 64);
    a2 += __shfl_down(a2, 32, 64); a3 += __shfl_down(a3, 32, 64);
    a0 += __shfl_down(a0, 16, 64); a1 += __shfl_down(a1, 16, 64);
    a2 += __shfl_down(a2, 16, 64); a3 += __shfl_down(a3, 16, 64);
    a0 += __shfl_down(a0, 8, 64);  a1 += __shfl_down(a1, 8, 64);
    a2 += __shfl_down(a2, 8, 64);  a3 += __shfl_down(a3, 8, 64);
    if (lane < 8) {
        uint2 sv = t2[(size_t)node * 8 + li];
        bfacc(sv, a0, a1, a2, a3);
        float dv = dinv[node];
        float4 o = {dv * a0, dv * a1, dv * a2, dv * a3};
        reinterpret_cast<float4*>(out)[(size_t)node * 8 + li] = o;
    }
}

// ---------------- tiled dense matmul: out[N,FOUT] = in[N,FIN] @ W + b --------
// Block = 64 rows. x tile staged in LDS (coalesced); lane = row, wave cg owns
// cols [cg*CW,(cg+1)*CW); W/bias via wave-uniform scalar loads.
// EXTRA: 0 = f32 out; 1 = outb=bf16(acc), outb2=bf16(dinv*relu(acc));
//        2 = outb=bf16(dinv*acc).
template <int FIN, int FOUT, bool HASBIAS, bool OUTRELU, int EXTRA>
__global__ __launch_bounds__(THREADS)
void k_mmt(const float* __restrict__ xin, const float* __restrict__ W,
           const float* __restrict__ bias, const float* __restrict__ dinv,
           float* __restrict__ out, unsigned* __restrict__ outb,
           unsigned* __restrict__ outb2, int nrows) {
    constexpr int FINQ = FIN / 4;
    constexpr int CW = FOUT / 4;      // cols per wave (4 waves)
    __shared__ float4 xs[64][FINQ + 1];
    int tid = threadIdx.x;
    int r0 = blockIdx.x * 64;
    const float4* xin4 = reinterpret_cast<const float4*>(xin);
    for (int i = tid; i < 64 * FINQ; i += THREADS) {
        int rr = i / FINQ, q = i - rr * FINQ;
        int grow = r0 + rr;
        float4 v = {0.f, 0.f, 0.f, 0.f};
        if (grow < nrows) v = xin4[(size_t)grow * FINQ + q];
        xs[rr][q] = v;
    }
    __syncthreads();
    int lane = tid & 63, cg = tid >> 6;
    int row = r0 + lane;
    int c0 = cg * CW;
    float acc[CW];
#pragma unroll
    for (int i = 0; i < CW; ++i) acc[i] = HASBIAS ? bias[c0 + i] : 0.f;
#pragma unroll 4
    for (int q = 0; q < FINQ; ++q) {
        float4 xv = xs[lane][q];
        const float* w0 = W + (size_t)(4 * q + 0) * FOUT + c0;
        const float* w1 = W + (size_t)(4 * q + 1) * FOUT + c0;
        const float* w2 = W + (size_t)(4 * q + 2) * FOUT + c0;
        const float* w3 = W + (size_t)(4 * q + 3) * FOUT + c0;
#pragma unroll
        for (int i = 0; i < CW; ++i) {
            acc[i] = fmaf(xv.x, w0[i], acc[i]);
            acc[i] = fmaf(xv.y, w1[i], acc[i]);
            acc[i] = fmaf(xv.z, w2[i], acc[i]);
            acc[i] = fmaf(xv.w, w3[i], acc[i]);
        }
    }
    if (row >= nrows) return;
    if (OUTRELU) {
#pragma unroll
        for (int i = 0; i < CW; ++i) acc[i] = fmaxf(acc[i], 0.f);
    }
    if (EXTRA == 0) {
        float4* op = reinterpret_cast<float4*>(out + (size_t)row * FOUT + c0);
#pragma unroll
        for (int i = 0; i < CW / 4; ++i) {
            float4 o = {acc[4 * i], acc[4 * i + 1], acc[4 * i + 2], acc[4 * i + 3]};
            op[i] = o;
        }
    }
    if (EXTRA == 1) {
        float dv = dinv[row];
        unsigned ub[CW / 2], us[CW / 2];
#pragma unroll
        for (int i = 0; i < CW / 2; ++i) {
            ub[i] = bfpack2(acc[2 * i], acc[2 * i + 1]);
            us[i] = bfpack2(dv * fmaxf(acc[2 * i], 0.f), dv * fmaxf(acc[2 * i + 1], 0.f));
        }
        uint4* bp = reinterpret_cast<uint4*>(outb + (size_t)row * (FOUT / 2) + c0 / 2);
        uint4* sp = reinterpret_cast<uint4*>(outb2 + (size_t)row * (FOUT / 2) + c0 / 2);
#pragma unroll
        for (int i = 0; i < CW / 8; ++i) {
            uint4 b4 = {ub[4 * i], ub[4 * i + 1], ub[4 * i + 2], ub[4 * i + 3]};
            uint4 s4 = {us[4 * i], us[4 * i + 1], us[4 * i + 2], us[4 * i + 3]};
            bp[i] = b4; sp[i] = s4;
        }
    }
    if (EXTRA == 2) {
        float dv = dinv[row];
        unsigned ub[CW / 2];
#pragma unroll
        for (int i = 0; i < CW / 2; ++i)
            ub[i] = bfpack2(dv * acc[2 * i], dv * acc[2 * i + 1]);
        uint4* bp = reinterpret_cast<uint4*>(outb + (size_t)row * (FOUT / 2) + c0 / 2);
#pragma unroll
        for (int i = 0; i < CW / 8; ++i) {
            uint4 b4 = {ub[4 * i], ub[4 * i + 1], ub[4 * i + 2], ub[4 * i + 3]};
            bp[i] = b4;
        }
    }
}

// ---------------- segment mean pool ----------------
__global__ __launch_bounds__(THREADS)
void k_pool(const float* __restrict__ h, const int* __restrict__ batch,
            float* __restrict__ sums, float* __restrict__ cnts, int n) {
    int c = threadIdx.x & 63;
    int rq = threadIdx.x >> 6;  // 0..3
    int r0 = blockIdx.x * THREADS;
    int rend = min(r0 + THREADS, n);
    int curg = -1;
    float acc = 0.f, cacc = 0.f;
    for (int r = r0 + rq; r < rend; r += 4) {
        int g = batch[r];
        if (g != curg) {
            if (curg >= 0) {
                atomicAdd(&sums[(size_t)curg * 64 + c], acc);
                if (c == 0) atomicAdd(&cnts[curg], cacc);
            }
            curg = g; acc = 0.f; cacc = 0.f;
        }
        acc += h[(size_t)r * 64 + c];
        cacc += 1.f;
    }
    if (curg >= 0) {
        atomicAdd(&sums[(size_t)curg * 64 + c], acc);
        if (c == 0) atomicAdd(&cnts[curg], cacc);
    }
}

__global__ __launch_bounds__(THREADS)
void k_div(const float* __restrict__ sums, const float* __restrict__ cnts,
           float* __restrict__ out, int total) {
    int i = blockIdx.x * THREADS + threadIdx.x;
    if (i < total) out[i] = sums[i] / cnts[i >> 6];
}

// ---------------------------------------------------------------------------
static inline size_t alignup(size_t v) { return (v + 255) & ~(size_t)255; }

extern "C" void kernel_launch(void* const* d_in, const int* in_sizes, int n_in,
                              void* d_out, int out_size, void* d_ws, size_t ws_size,
                              hipStream_t stream) {
    const float* ev_f  = (const float*)d_in[0];
    const float* cs_f  = (const float*)d_in[1];
    const float* tr_f  = (const float*)d_in[2];
    const float* env_f = (const float*)d_in[3];
    const int*   ei    = (const int*)d_in[4];
    const int*   ev_i  = (const int*)d_in[5];
    const int*   cs_i  = (const int*)d_in[6];
    const int*   tr_i  = (const int*)d_in[7];
    const int*   env_i = (const int*)d_in[8];
    const int*   batch = (const int*)d_in[9];
    const float* W_ev = (const float*)d_in[10]; const float* b_ev = (const float*)d_in[11];
    const float* W_cs = (const float*)d_in[12]; const float* b_cs = (const float*)d_in[13];
    const float* W_tr = (const float*)d_in[14]; const float* b_tr = (const float*)d_in[15];
    const float* W_env= (const float*)d_in[16]; const float* b_env= (const float*)d_in[17];
    const float* W1 = (const float*)d_in[18]; const float* b1 = (const float*)d_in[19];
    const float* W2 = (const float*)d_in[20]; const float* b2 = (const float*)d_in[21];
    const float* W3 = (const float*)d_in[22]; const float* b3 = (const float*)d_in[23];

    const int E_ = in_sizes[4] / 2;
    const int N_ = in_sizes[9];
    const int n_ev  = in_sizes[5];
    const int n_cs  = in_sizes[6];
    const int n_tr  = in_sizes[7];
    const int n_env = in_sizes[8];
    const int ngr   = out_size / 64;  // 100 graphs

    const int* e_src = ei;
    const int* e_dst = ei + E_;

    const int NB   = (N_ + (1 << BINSHIFT) - 1) >> BINSHIFT;  // 98 bins
    const int ablk = (E_ + EPBA - 1) / EPBA;                  // 782 partition blocks

    // ---- workspace carve-up ----
    char* p = (char*)d_ws;
    int*      counts = (int*)p;      p += alignup((size_t)NB * ablk * 4);
    int*      bintot = (int*)p;      p += alignup((size_t)NB * 4);
    int*      binptr = (int*)p;      p += alignup(((size_t)NB + 1) * 4);
    int*      rowptr = (int*)p;      p += alignup(((size_t)N_ + 1) * 4);
    float*    dinv   = (float*)p;    p += alignup((size_t)N_ * 4);
    int*      srcs   = (int*)p;      p += alignup((size_t)E_ * 4);
    unsigned* xb     = (unsigned*)p; p += alignup((size_t)N_ * 16 * 4);   // bf16 [N,32]
    unsigned* x1b    = (unsigned*)p; p += alignup((size_t)N_ * 32 * 4);   // bf16 [N,64] raw x1
    float*    bufB   = (float*)p;    p += alignup((size_t)N_ * 64 * 4);
    float*    bufA   = (float*)p;    p += alignup((size_t)N_ * 128 * 4);
    float*    sums   = (float*)p;    p += alignup((size_t)ngr * 64 * 4);
    float*    cnts   = (float*)p;    p += alignup((size_t)ngr * 4);

    // Aliases into dead regions of bufA / bufB:
    //  pairs  (E u32 = 12.8MB)   -> bufA (dies at k_bincsr; bufA next written by mm2)
    //  x1s_bf (N*32 u32 = 12.8MB)-> bufA (mm1 -> gather2; mm2 writes bufA after)
    //  t3s_bf (N*32 u32 = 12.8MB)-> bufB (bufB dead after mm2 reads it; mm3 writes,
    //                               gather3 reads; gather3 writes bufA)
    unsigned* pairs  = (unsigned*)bufA;
    unsigned* x1s_bf = (unsigned*)bufA;
    unsigned* t3s_bf = (unsigned*)bufB;

    const int nblk = (N_ + THREADS - 1) / THREADS;
    const int mblk = (N_ + 63) / 64;                                // 64 rows/block
    const int gblk = ((size_t)N_ * 64 + THREADS - 1) / THREADS;     // wave/node

    // ---- zero accumulated buffers (fresh every call) ----
    hipMemsetAsync(sums, 0, (size_t)ngr * 64 * 4, stream);
    hipMemsetAsync(cnts, 0, (size_t)ngr * 4, stream);

    // ---- CSR build (atomic-free partition) ----
    k_partcnt<<<ablk, THREADS, (size_t)NB * 4, stream>>>(e_dst, counts, ablk, NB, E_);
    k_scanrows<<<NB, THREADS, 0, stream>>>(counts, bintot, ablk);
    k_binscan<<<1, 128, 0, stream>>>(bintot, binptr, NB, E_);
    k_partwrite<<<ablk, THREADS, (size_t)NB * 8, stream>>>(e_src, e_dst, binptr, counts, ablk, pairs, NB, E_);
    k_bincsr<<<NB, THREADS, 0, stream>>>(pairs, binptr, rowptr, dinv, srcs, N_, NB, E_);

    // ---- embeddings -> xb [N,32] bf16 (pre-scaled by dinv) ----
    k_embed<6><<<((size_t)n_ev  * 16 + THREADS - 1) / THREADS, THREADS, 0, stream>>>(ev_f,  W_ev,  b_ev,  ev_i,  dinv, n_ev,  xb);
    k_embed<4><<<((size_t)n_cs  * 16 + THREADS - 1) / THREADS, THREADS, 0, stream>>>(cs_f,  W_cs,  b_cs,  cs_i,  dinv, n_cs,  xb);
    k_embed<2><<<((size_t)n_tr  * 16 + THREADS - 1) / THREADS, THREADS, 0, stream>>>(tr_f,  W_tr,  b_tr,  tr_i,  dinv, n_tr,  xb);
    k_embed<5><<<((size_t)n_env * 16 + THREADS - 1) / THREADS, THREADS, 0, stream>>>(env_f, W_env, b_env, env_i, dinv, n_env, xb);

    // ---- conv1: agg(xb) -> bufB f32; mm1: x1b = bf16(x1), x1s_bf = bf16(dinv*relu(x1)) ----
    k_gather32<<<gblk, THREADS, 0, stream>>>(xb, rowptr, srcs, dinv, bufB, N_);
    k_mmt<32, 64, true, false, 1><<<mblk, THREADS, 0, stream>>>(
        bufB, W1, b1, dinv, nullptr, x1b, x1s_bf, N_);

    // ---- conv2: agg(x1s_bf) -> bufB; mm2: relu(bufB @ W2 + b2) -> bufA [N,128] ----
    k_gather64<false, false, false><<<gblk, THREADS, 0, stream>>>(
        x1s_bf, rowptr, srcs, dinv, nullptr, nullptr, bufB, N_);
    k_mmt<64, 128, true, true, 0><<<mblk, THREADS, 0, stream>>>(
        bufB, W2, b2, nullptr, bufA, nullptr, nullptr, N_);

    // ---- conv3: mm3: t3s_bf = bf16(dinv*(bufA @ W3)); gather3: relu(agg+b3)+x1b -> bufA ----
    k_mmt<128, 64, false, false, 2><<<mblk, THREADS, 0, stream>>>(
        bufA, W3, nullptr, dinv, nullptr, t3s_bf, nullptr, N_);
    k_gather64<true, true, true><<<gblk, THREADS, 0, stream>>>(
        t3s_bf, rowptr, srcs, dinv, b3, x1b, bufA, N_);

    // ---- pool ----
    k_pool<<<nblk, THREADS, 0, stream>>>(bufA, batch, sums, cnts, N_);
    k_div<<<(out_size + THREADS - 1) / THREADS, THREADS, 0, stream>>>(sums, cnts, (float*)d_out, out_size);
}